// Round 15
// baseline (61.572 us; speedup 1.0000x reference)
//
#include <hip/hip_runtime.h>
#include <hip/hip_bf16.h>
#include <math.h>

#define NP 4096     // GRID*GRID
#define NA 256      // stim channels

typedef unsigned short ushort_t;
typedef __attribute__((ext_vector_type(8))) short short8;
typedef __attribute__((ext_vector_type(4))) float f32x4;
typedef __attribute__((ext_vector_type(4))) unsigned short ushort4v;
typedef __attribute__((ext_vector_type(8))) unsigned short ushort8v;

__device__ __forceinline__ ushort_t f2bf(float x) {
    __hip_bfloat16 h = __float2bfloat16(x);
    return *reinterpret_cast<ushort_t*>(&h);
}
__device__ __forceinline__ float bf2f(ushort_t u) {
    unsigned x = ((unsigned)u) << 16;
    return __builtin_bit_cast(float, x);
}

// ---------------------------------------------------------------------------
// setup_all (r11-verified), grid 448 x 512 thr:
//  blocks [0,256):   stim [4096 g][256 a] f32 -> stimT [256 a][4096 g] bf16
//  blocks [256,448): table images, one (field f, p-block pblk) per block:
//    gxbI [f][pblk][64 row][64 j]  bf16  — per-lane MFMA B-frag-ready
//    gy2I [f][pblk][4096]          f32   — pre-swizzled lgy2 image
//    attI [4096]                   f32   (f==0 only)
// ---------------------------------------------------------------------------
__global__ __launch_bounds__(512)
void setup_all(const float* __restrict__ stim,
               const float* __restrict__ pscale,
               const float* __restrict__ pasig,
               const float* __restrict__ pagain,
               const float* __restrict__ pssf,
               const float* __restrict__ psff,
               ushort_t* __restrict__ stimT,
               ushort_t* __restrict__ gxbI,
               float* __restrict__ gy2I,
               float* __restrict__ attI)
{
    __shared__ float lt[64 * 68];
    const int t = threadIdx.x;
    const int bx = blockIdx.x;
    const float step = 20.0f / 63.0f;

    if (bx < 256) {
        const int g0 = (bx & 63) * 64, a0 = (bx >> 6) * 64;
        const int gr = t >> 3, ar = (t & 7) * 8;
        *(f32x4*)&lt[gr * 68 + ar]     = *(const f32x4*)&stim[(size_t)(g0 + gr) * NA + a0 + ar];
        *(f32x4*)&lt[gr * 68 + ar + 4] = *(const f32x4*)&stim[(size_t)(g0 + gr) * NA + a0 + ar + 4];
        __syncthreads();
        const int a = t >> 3, c8 = (t & 7) * 8;
        ushort8v u;
        #pragma unroll
        for (int i = 0; i < 8; ++i) u[i] = f2bf(lt[(c8 + i) * 68 + a]);
        *(ushort8v*)&stimT[(size_t)(a0 + a) * NP + g0 + c8] = u;
    } else {
        const int b    = bx - 256;        // 0..191
        const int f    = b >> 6;          // 0..2
        const int pblk = b & 63;
        const int w    = t >> 6;
        const int l    = t & 63;
        const float sc_scale = pscale[0];
        const float fac = (f == 0) ? 1.0f : (f == 1 ? pssf[0] : psff[0]);
        const float coord = -10.0f + step * (float)l;
        ushort_t* gxb = gxbI + ((size_t)f * 64 + pblk) * 4096;
        float*    gy2 = gy2I + ((size_t)f * 64 + pblk) * 4096;

        #pragma unroll
        for (int i = 0; i < 8; ++i) {
            const int pl = w * 8 + i, p = pblk * 64 + pl;
            float cx = -10.0f + step * (float)(p & 63);
            float cy = -10.0f + step * (float)(p >> 6);
            float sg = (0.07f + sc_scale * sqrtf(cx * cx + cy * cy)) * fac;
            float inv = 1.0f / (2.0f * sg * sg);
            float dx = coord - cx, dy = coord - cy;
            float ex = expf(-dx * dx * inv);
            float ey = expf(-dy * dy * inv);
            float sx = ex, sy = ey;
            #pragma unroll
            for (int o = 32; o > 0; o >>= 1) {
                sx += __shfl_xor(sx, o);
                sy += __shfl_xor(sy, o);
            }
            gxb[pl * 64 + l] = f2bf(ex / sx);                       // coalesced
            // pre-swizzled lgy2 image (l = gi):
            gy2[l * 64 + (((pl & 15) * 4) ^ ((l & 7) << 3)) + (pl >> 4)] = ey / sy;
            if (f == 0 && l == 0) {
                float asig = pasig[0];
                float d2 = (cx - 3.0f) * (cx - 3.0f) + cy * cy;
                attI[p] = pagain[0] * expf(-d2 / (2.0f * asig * asig)) + 1.0f;
            }
        }
    }
}

// ---------------------------------------------------------------------------
// 16-wave barrier-free wave-private GEMM (4 waves/SIMD).
// C^T[a,p] = sum_g B[g,a]*gy[p][gi]*gx[p][gj]
// wave = (asub = w>>2, kq = w&3); per step tt (16 steps x 256 g) it stages and
// consumes gi = 4*tt+kq for its 16 a-rows. lB[4 buf][4 kq][4 asub][16][64]
// bf16 = 128 KB, NBUF=4 ring, stage distance 3, per-wave counted vmcnt(2)
// (tile tt+1 landed, tile tt+2 outstanding), tail 2/2/0/0. No K-loop barriers.
// Reg ping-pong Aa/Ab + s4a/s4b as r14. 4-way K-reduce in dead lB.
// acc[pt][r]:  p = p0 + pt*16 + r16 (MFMA col),  a = a0 + asub*16 + q*4 + r.
// MODE 0: C=num=dot*att[p], CT=bf16(num)^T
// MODE 1: C=surr=dot; C2=pn=num/(surr+.5); CT=bf16(pn)^T
// MODE 2: C=pv=dot
// ---------------------------------------------------------------------------
template <int MODE>
__global__ __launch_bounds__(1024)
void field_gemm(const ushort_t* __restrict__ bT,
                const ushort_t* __restrict__ gxbF,   // field-offset image
                const float* __restrict__ gy2F,      // field-offset image
                const float* __restrict__ attI,
                const float* __restrict__ num,       // MODE 1 input
                float* __restrict__ C,
                float* __restrict__ C2,
                ushort_t* __restrict__ CT,
                const ushort_t* __restrict__ numTsrc)
{
    __shared__ __align__(16) unsigned char smem[147712];
    ushort_t* lB   = (ushort_t*)smem;             // [4][4 kq][4 asub][16][64]
    float*    lgy2 = (float*)(smem + 131072);
    float*    latt = (float*)(smem + 147456);

    const int t    = threadIdx.x;
    const int w    = t >> 6;          // 0..15
    const int l    = t & 63;
    const int asub = w >> 2;          // 0..3
    const int kq   = w & 3;           // K-quarter
    const int r16  = l & 15;
    const int q    = l >> 4;
    const int srow  = l >> 3;         // 0..7
    const int sslot = (l & 7) ^ (srow & 7);
    const int base_w = kq * 4096 + asub * 1024;   // wave region (ushorts)

    // XCD-clustered bijective tile swizzle (256 blocks, 8 XCDs)
    const int v    = blockIdx.x;
    const int lid  = (v & 7) * 32 + (v >> 3);
    const int pblk = lid & 63;
    const int p0   = pblk * 64;
    const int a0   = (lid >> 6) * 64;

    // wave-private stage of tile tn's (kq, asub) slice: 2 x 1KB DMA
#define STAGE(buf, tn)                                                         \
    _Pragma("unroll")                                                          \
    for (int h = 0; h < 2; ++h) {                                              \
        const ushort_t* src = bT + (size_t)(a0 + asub * 16 + h * 8 + srow) * NP\
                              + (4 * (tn) + kq) * 64 + sslot * 8;              \
        ushort_t* dst = lB + (buf) * 16384 + base_w + h * 512;                 \
        __builtin_amdgcn_global_load_lds(                                      \
            (const __attribute__((address_space(1))) unsigned int*)src,        \
            (__attribute__((address_space(3))) unsigned int*)dst, 16, 0, 0);   \
    }

    // prologue: 3 tiles in flight + tables (one drain for everything)
    STAGE(0, 0); STAGE(1, 1); STAGE(2, 2);

    {   // lgy2: verbatim DMA copy of the pre-swizzled image (16 KB, 16 waves)
        const float* src = gy2F + (size_t)pblk * 4096 + w * 256 + l * 4;
        float* dst = lgy2 + w * 256;
        __builtin_amdgcn_global_load_lds(
            (const __attribute__((address_space(1))) unsigned int*)src,
            (__attribute__((address_space(3))) unsigned int*)dst, 16, 0, 0);
    }
    if (MODE == 0 && w == 0) {
        const float* src = attI + p0 + l;
        __builtin_amdgcn_global_load_lds(
            (const __attribute__((address_space(1))) unsigned int*)src,
            (__attribute__((address_space(3))) unsigned int*)latt, 4, 0, 0);
    }

    // B-operand fragments (gx): straight register loads from the bf16 image
    const ushort_t* gxb = gxbF + (size_t)pblk * 4096;
    short8 gxf[4][2];
    #pragma unroll
    for (int pt = 0; pt < 4; ++pt) {
        const int row = pt * 16 + r16;
        gxf[pt][0] = *(const short8*)&gxb[row * 64 + q * 8];
        gxf[pt][1] = *(const short8*)&gxb[row * 64 + 32 + q * 8];
    }

    __syncthreads();   // single rendezvous: drains ALL prologue vmem (vmcnt=0)

    const int bo0 = r16 * 64 + ((q ^ (r16 & 7)) * 8);        // k 0..31
    const int bo1 = r16 * 64 + (((4 + q) ^ (r16 & 7)) * 8);  // k 32..63

    f32x4 acc[4];
    #pragma unroll
    for (int pt = 0; pt < 4; ++pt) acc[pt] = (f32x4){0.f, 0.f, 0.f, 0.f};

    // explicit ping-pong register sets (rule #20)
    short8 Aa0, Aa1, Ab0, Ab1;
    f32x4 s4a, s4b;
    {   // step-0 operands (tiles 0..2 resident post-sync)
        const ushort_t* bb0 = lB + base_w;          // buf 0
        Aa0 = *(const short8*)(bb0 + bo0);
        Aa1 = *(const short8*)(bb0 + bo1);
        const int gi0 = kq;
        s4a = *(const f32x4*)(lgy2 + gi0 * 64 + ((r16 * 4) ^ ((gi0 & 7) << 3)));
    }

#define STEP(TT, VM, CA0, CA1, CS4, NA0, NA1, NS4, PRE, ST)                    \
    {                                                                          \
        const int tt_k = (TT);                                                 \
        asm volatile("s_waitcnt vmcnt(" #VM ")" ::: "memory");                 \
        if (PRE) {                                                             \
            const ushort_t* bbn = lB + ((tt_k + 1) & 3) * 16384 + base_w;      \
            NA0 = *(const short8*)(bbn + bo0);                                 \
            NA1 = *(const short8*)(bbn + bo1);                                 \
            const int gin = 4 * (tt_k + 1) + kq;                               \
            NS4 = *(const f32x4*)(lgy2 + gin * 64 +                            \
                                  ((r16 * 4) ^ ((gin & 7) << 3)));             \
        }                                                                      \
        if (ST) { STAGE((tt_k + 3) & 3, tt_k + 3); }                           \
        __builtin_amdgcn_s_setprio(1);                                         \
        _Pragma("unroll")                                                      \
        for (int pt = 0; pt < 4; ++pt) {                                       \
            f32x4 tmp = (f32x4){0.f, 0.f, 0.f, 0.f};                           \
            tmp = __builtin_amdgcn_mfma_f32_16x16x32_bf16(CA0, gxf[pt][0], tmp, 0, 0, 0); \
            tmp = __builtin_amdgcn_mfma_f32_16x16x32_bf16(CA1, gxf[pt][1], tmp, 0, 0, 0); \
            float sc = CS4[pt];                                                \
            acc[pt] += tmp * sc;                                               \
        }                                                                      \
        __builtin_amdgcn_s_setprio(0);                                         \
    }

    #pragma unroll
    for (int pi = 0; pi < 6; ++pi) {        // tt = 0..11 (all stage)
        STEP(2 * pi,     2, Aa0, Aa1, s4a, Ab0, Ab1, s4b, 1, 1);
        STEP(2 * pi + 1, 2, Ab0, Ab1, s4b, Aa0, Aa1, s4a, 1, 1);
    }
    STEP(12, 2, Aa0, Aa1, s4a, Ab0, Ab1, s4b, 1, 1);   // stage tile 15
    STEP(13, 2, Ab0, Ab1, s4b, Aa0, Aa1, s4a, 1, 0);
    STEP(14, 0, Aa0, Aa1, s4a, Ab0, Ab1, s4b, 1, 0);
    STEP(15, 0, Ab0, Ab1, s4b, Aa0, Aa1, s4a, 0, 0);
#undef STEP
#undef STAGE

    // ---- epilogue: 4-way K-reduce via dual-layout LDS (aliases dead lB) ----
    __syncthreads();   // all waves drained + lB/lgy2 reads done
    float* lred_pa = (float*)smem;              // [4 kq][64 p][68 a]
    float* lred_ap = (float*)(smem + 69632);    // [4 kq][64 a][68 p]

    const int a_base = asub * 16 + q * 4;       // acc[pt][r] -> a = a_base + r
    #pragma unroll
    for (int pt = 0; pt < 4; ++pt) {
        const int p_idx = pt * 16 + r16;        // acc[pt][*] -> p = p_idx
        *(f32x4*)&lred_pa[(kq * 64 + p_idx) * 68 + a_base] = acc[pt];
        #pragma unroll
        for (int r = 0; r < 4; ++r)
            lred_ap[(kq * 64 + a_base + r) * 68 + p_idx] = acc[pt][r];
    }
    __syncthreads();

    // pass A: a-major -> CT (bf16 transposed), 8B/lane coalesced
    if (MODE != 2) {
        const int aL = t >> 4, p4 = (t & 15) * 4;
        f32x4 s0 = *(f32x4*)&lred_ap[aL * 68 + p4] +
                   *(f32x4*)&lred_ap[(64 + aL) * 68 + p4] +
                   *(f32x4*)&lred_ap[(128 + aL) * 68 + p4] +
                   *(f32x4*)&lred_ap[(192 + aL) * 68 + p4];
        ushort4v cv;
        if (MODE == 0) {
            s0 *= *(f32x4*)&latt[p4];
            #pragma unroll
            for (int r = 0; r < 4; ++r) cv[r] = f2bf(s0[r]);
        } else {
            ushort4v nt = *(const ushort4v*)&numTsrc[(size_t)(a0 + aL) * NP + p0 + p4];
            #pragma unroll
            for (int r = 0; r < 4; ++r)
                cv[r] = f2bf(bf2f(nt[r]) / (s0[r] + 0.5f));
        }
        *(ushort4v*)&CT[(size_t)(a0 + aL) * NP + p0 + p4] = cv;
    }

    // pass B: p-major -> C (f32), 16B/lane coalesced
    {
        const int pL = t >> 4, a4 = (t & 15) * 4;
        f32x4 s0 = *(f32x4*)&lred_pa[pL * 68 + a4] +
                   *(f32x4*)&lred_pa[(64 + pL) * 68 + a4] +
                   *(f32x4*)&lred_pa[(128 + pL) * 68 + a4] +
                   *(f32x4*)&lred_pa[(192 + pL) * 68 + a4];
        float* cbase = C + (size_t)(p0 + pL) * NA + a0 + a4;
        if (MODE == 0) {
            s0 *= latt[pL];
            *(f32x4*)cbase = s0;
        } else if (MODE == 1) {
            *(f32x4*)cbase = s0;                      // surround
            f32x4 n0 = *(const f32x4*)(num + (size_t)(p0 + pL) * NA + a0 + a4);
            f32x4 o0 = n0 / (s0 + 0.5f);
            *(f32x4*)(C2 + (size_t)(p0 + pL) * NA + a0 + a4) = o0;  // pn
        } else {
            *(f32x4*)cbase = s0;                      // predicted_voxel
        }
    }
}

extern "C" void kernel_launch(void* const* d_in, const int* in_sizes, int n_in,
                              void* d_out, int out_size, void* d_ws, size_t ws_size,
                              hipStream_t stream)
{
    const float* stim   = (const float*)d_in[0];
    const float* pscale = (const float*)d_in[1];
    const float* pasig  = (const float*)d_in[2];
    const float* pagain = (const float*)d_in[3];
    const float* pssf   = (const float*)d_in[4];
    const float* psff   = (const float*)d_in[5];

    float* out  = (float*)d_out;
    float* num  = out;
    float* surr = out + (size_t)NP * NA;
    float* pn   = out + 2 * (size_t)NP * NA;
    float* pv   = out + 3 * (size_t)NP * NA;

    // ws layout
    ushort_t* stimT = (ushort_t*)d_ws;                    // 2 MB
    ushort_t* numT  = stimT + (size_t)NA * NP;            // 2 MB
    ushort_t* pnT   = numT + (size_t)NA * NP;             // 2 MB
    ushort_t* gxbI  = pnT + (size_t)NA * NP;              // 1.5 MB (3*64*4096 bf16)
    float*    gy2I  = (float*)(gxbI + (size_t)3 * 64 * 4096);  // 3 MB
    float*    attI  = gy2I + (size_t)3 * 64 * 4096;       // 16 KB

    setup_all<<<448, 512, 0, stream>>>(stim, pscale, pasig, pagain, pssf, psff,
                                       stimT, gxbI, gy2I, attI);

    const ushort_t* gx0 = gxbI;
    const ushort_t* gx1 = gxbI + (size_t)64 * 4096;
    const ushort_t* gx2 = gxbI + (size_t)128 * 4096;
    const float*    gy0 = gy2I;
    const float*    gy1 = gy2I + (size_t)64 * 4096;
    const float*    gy2 = gy2I + (size_t)128 * 4096;

    field_gemm<0><<<256, 1024, 0, stream>>>(stimT, gx0, gy0, attI, nullptr,
                                            num, nullptr, numT, nullptr);
    field_gemm<1><<<256, 1024, 0, stream>>>(numT, gx1, gy1, attI, num,
                                            surr, pn, pnT, numT);
    field_gemm<2><<<256, 1024, 0, stream>>>(pnT, gx2, gy2, attI, nullptr,
                                            pv, nullptr, nullptr, nullptr);
}